// Round 7
// baseline (262.246 us; speedup 1.0000x reference)
//
#include <hip/hip_runtime.h>
#include <hip/hip_fp16.h>

#define N_NODES   100000
#define N_EDGES   1600000
#define IN_CH     128
#define HID       64
#define N_CLASSES 16
#define N_GRAPHS  64

#define BK_SH     9                          // bucket = dst >> 9 (512 nodes/bucket)
#define BK_NODES  512
#define NB        ((N_NODES + BK_NODES - 1) / BK_NODES)   // 196 buckets
#define BK_CAP    10240                      // fixed bucket capacity (mean 8163, +23 sigma)
#define CH_EDGES  4096
#define EPT       16                         // edges/thread in binscatter (256 thr)
#define NCH       ((N_EDGES + CH_EDGES - 1) / CH_EDGES)   // 391 chunks
#define AGG_NPW   2    // nodes per wave; 12500 blocks x 8 nodes = exact cover

typedef __attribute__((ext_vector_type(8))) short bf16x8;
typedef __attribute__((ext_vector_type(4))) float f32x4;
typedef __attribute__((ext_vector_type(4))) unsigned u32x4;
typedef __attribute__((ext_vector_type(2))) unsigned u32x2;

__device__ __forceinline__ unsigned short f2bf(float f) {   // RNE f32->bf16
    unsigned u = __float_as_uint(f);
    u += 0x7fffu + ((u >> 16) & 1u);
    return (unsigned short)(u >> 16);
}
__device__ __forceinline__ f32x4 bf4v(uint2 v) {            // 4 bf16 -> f32x4
    u32x4 u;
    u.x = v.x << 16; u.y = v.x & 0xffff0000u;
    u.z = v.y << 16; u.w = v.y & 0xffff0000u;
    return __builtin_bit_cast(f32x4, u);
}
// csr entry: src (17 bits) | fp16(ew) sign-free (15 bits) << 17
__device__ __forceinline__ float dec_ew(unsigned v) {
    return __half2float(__ushort_as_half((unsigned short)(v >> 17)));
}

// ---- SRSRC buffer view: 32-bit voffset addressing for random gathers ----
#if __has_builtin(__builtin_amdgcn_make_buffer_rsrc) && \
    __has_builtin(__builtin_amdgcn_raw_buffer_load_b32) && \
    __has_builtin(__builtin_amdgcn_raw_buffer_load_b64)
struct BufView {
    __amdgpu_buffer_rsrc_t rsrc;
    __device__ __forceinline__ void init(const void* p) {
        rsrc = __builtin_amdgcn_make_buffer_rsrc((void*)p, (short)0,
                                                 (int)0xFFFFFFFF, 0x00020000);
    }
    __device__ __forceinline__ unsigned ld32(unsigned off) const {
        return __builtin_amdgcn_raw_buffer_load_b32(rsrc, (int)off, 0, 0);
    }
    __device__ __forceinline__ uint2 ld64(unsigned off) const {
        u32x2 r = __builtin_amdgcn_raw_buffer_load_b64(rsrc, (int)off, 0, 0);
        return make_uint2(r.x, r.y);
    }
};
#else
struct BufView {
    const char* base;
    __device__ __forceinline__ void init(const void* p) { base = (const char*)p; }
    __device__ __forceinline__ unsigned ld32(unsigned off) const {
        return *(const unsigned*)(base + off);
    }
    __device__ __forceinline__ uint2 ld64(unsigned off) const {
        return *(const uint2*)(base + off);
    }
};
#endif

// ---------------------------------------------------------------- init
__global__ void k_init(int* __restrict__ bcursor, float* __restrict__ pooled) {
    int i = blockIdx.x * 256 + threadIdx.x;
    if (i < NB) bcursor[i] = i * BK_CAP;
    if (i < N_GRAPHS * HID) pooled[i] = 0.0f;
}

// ---------------------------------------------------------------- bin scatter (staged)
__global__ void k_binscatter(const int* __restrict__ src, const int* __restrict__ dst,
                             const float* __restrict__ ew, int* __restrict__ bcursor,
                             int2* __restrict__ bedges) {
    __shared__ int  hist[NB];
    __shared__ int  offs[NB];
    __shared__ int  gbase[NB];
    __shared__ int  sc[256];
    __shared__ int2 stage[CH_EDGES];
    __shared__ int  dest[CH_EDGES];
    const int t = threadIdx.x;
    const int base = blockIdx.x * CH_EDGES;
    const int nloc = min(CH_EDGES, N_EDGES - base);

    for (int i = t; i < NB; i += 256) hist[i] = 0;
    __syncthreads();

    int myb[EPT], myr[EPT], myp[EPT]; float myw[EPT];
#pragma unroll
    for (int j = 0; j < EPT; ++j) {
        int i = base + j * 256 + t;
        if (i < N_EDGES) {
            int s = src[i], d = dst[i];
            int b = d >> BK_SH;
            myb[j] = b;
            myr[j] = atomicAdd(&hist[b], 1);
            myp[j] = s | ((d & (BK_NODES - 1)) << 17);
            myw[j] = ew[i];
        } else {
            myb[j] = -1;
        }
    }
    __syncthreads();

    int v = (t < NB) ? hist[t] : 0;
    sc[t] = v;
    __syncthreads();
    for (int off = 1; off < 256; off <<= 1) {
        int a = (t >= off) ? sc[t - off] : 0;
        __syncthreads();
        sc[t] += a;
        __syncthreads();
    }
    if (t < NB) {
        offs[t] = sc[t] - v;
        gbase[t] = (v > 0) ? atomicAdd(&bcursor[t], v) : 0;
    }
    __syncthreads();

#pragma unroll
    for (int j = 0; j < EPT; ++j) {
        if (myb[j] >= 0) {
            int p = offs[myb[j]] + myr[j];
            stage[p] = make_int2(myp[j], __float_as_int(myw[j]));
            dest[p] = gbase[myb[j]] + myr[j];
        }
    }
    __syncthreads();

    for (int i = t; i < nloc; i += 256)
        bedges[dest[i]] = stage[i];
}

// ---------------------------------------------------------------- build (fused)
__global__ __launch_bounds__(256) void k_build(const int* __restrict__ bcursor,
                                               const int2* __restrict__ bedges,
                                               int2* __restrict__ rowse,
                                               float* __restrict__ dis,
                                               unsigned* __restrict__ csr) {
    __shared__ int2  eds[BK_CAP];         // 80 KB
    __shared__ int   cnt[BK_NODES];
    __shared__ float dsum[BK_NODES];
    __shared__ int   cur[BK_NODES];
    __shared__ int   sc[256];
    const int b = blockIdx.x;
    const int t = threadIdx.x;
    const int beg = b * BK_CAP, end = bcursor[b];
    const int n = end - beg;

    for (int i = t; i < BK_NODES; i += 256) { cnt[i] = 0; dsum[i] = 0.0f; }
    __syncthreads();

    for (int i = t; i < n; i += 256) {
        int2 e = bedges[beg + i];
        eds[i] = e;
        int dl = ((unsigned)e.x) >> 17;
        atomicAdd(&cnt[dl], 1);
        atomicAdd(&dsum[dl], __int_as_float(e.y));
    }
    __syncthreads();

    int a0 = cnt[2 * t], a1 = cnt[2 * t + 1];
    int pair = a0 + a1;
    sc[t] = pair;
    __syncthreads();
    for (int off = 1; off < 256; off <<= 1) {
        int a = (t >= off) ? sc[t - off] : 0;
        __syncthreads();
        sc[t] += a;
        __syncthreads();
    }
    int excl = sc[t] - pair;
    cur[2 * t] = excl;
    cur[2 * t + 1] = excl + a0;
    {
        int n0 = b * BK_NODES + 2 * t;
        if (n0 < N_NODES) {
            rowse[n0] = make_int2(beg + excl, beg + excl + a0);
            dis[n0] = rsqrtf(1.0f + dsum[2 * t]);
        }
        int n1 = n0 + 1;
        if (n1 < N_NODES) {
            rowse[n1] = make_int2(beg + excl + a0, beg + excl + a0 + a1);
            dis[n1] = rsqrtf(1.0f + dsum[2 * t + 1]);
        }
    }
    __syncthreads();

    for (int i = t; i < n; i += 256) {
        int2 e = eds[i];
        int dl = ((unsigned)e.x) >> 17;
        int s = e.x & 0x1FFFF;
        unsigned short w16 = __half_as_ushort(__float2half(__int_as_float(e.y)));
        int pos = beg + atomicAdd(&cur[dl], 1);
        csr[pos] = (unsigned)s | ((unsigned)w16 << 17);
    }
}

// ---------------------------------------------------------------- GEMM via MFMA
// Epilogue scales by dis[row]: hb = bf16(dis * (x@W))  [norm factoring]
// INB=true: input is row-major bf16 [N][K] -> A-fragments loaded straight
// from global (no LDS staging, no conversion).
template <int K, bool INB>
__global__ __launch_bounds__(256) void k_gemm(const float* __restrict__ x,
                                              const unsigned short* __restrict__ xb,
                                              const float* __restrict__ W,
                                              const float* __restrict__ dis,
                                              unsigned short* __restrict__ hb) {
    constexpr int AS = K + 8;            // padded stride in bf16 elems
    __shared__ unsigned short wt[64 * AS];    // wt[n][k] = W[k][n]
    const int t    = threadIdx.x;
    const int lane = t & 63;
    const int wave = t >> 6;
    const int m    = lane & 15;
    const int quad = lane >> 4;
    const int rowbase = blockIdx.x * 64;

    bf16x8 afrag[K / 32];

    if constexpr (!INB) {
        __shared__ unsigned short a_s[64 * AS];   // a_s[row][k]
        constexpr int CPR = K / 8;
        for (int c = t; c < 64 * CPR; c += 256) {
            int row = c / CPR, cc = c % CPR;
            int gr = rowbase + row;
            float4 v0, v1;
            if (gr < N_NODES) {
                v0 = *(const float4*)&x[(long)gr * K + cc * 8];
                v1 = *(const float4*)&x[(long)gr * K + cc * 8 + 4];
            } else {
                v0 = make_float4(0.f, 0.f, 0.f, 0.f); v1 = v0;
            }
            uint4 p;
            p.x = f2bf(v0.x) | ((unsigned)f2bf(v0.y) << 16);
            p.y = f2bf(v0.z) | ((unsigned)f2bf(v0.w) << 16);
            p.z = f2bf(v1.x) | ((unsigned)f2bf(v1.y) << 16);
            p.w = f2bf(v1.z) | ((unsigned)f2bf(v1.w) << 16);
            *(uint4*)&a_s[row * AS + cc * 8] = p;
        }
        for (int idx = t; idx < K * 64; idx += 256) {
            int k = idx >> 6, n = idx & 63;
            wt[n * AS + k] = f2bf(W[idx]);
        }
        __syncthreads();
#pragma unroll
        for (int ks = 0; ks < K / 32; ++ks)
            afrag[ks] = *(const bf16x8*)&a_s[(wave * 16 + m) * AS + ks * 32 + quad * 8];
    } else {
        const int gr = rowbase + wave * 16 + m;
#pragma unroll
        for (int ks = 0; ks < K / 32; ++ks) {
            if (gr < N_NODES)
                afrag[ks] = *(const bf16x8*)&xb[(long)gr * K + ks * 32 + quad * 8];
            else
                afrag[ks] = (bf16x8){0, 0, 0, 0, 0, 0, 0, 0};
        }
        for (int idx = t; idx < K * 64; idx += 256) {
            int k = idx >> 6, n = idx & 63;
            wt[n * AS + k] = f2bf(W[idx]);
        }
        __syncthreads();
    }

    bf16x8 bfrag[4][K / 32];
#pragma unroll
    for (int nt = 0; nt < 4; ++nt)
#pragma unroll
        for (int ks = 0; ks < K / 32; ++ks)
            bfrag[nt][ks] = *(const bf16x8*)&wt[(nt * 16 + m) * AS + ks * 32 + quad * 8];

    f32x4 acc[4];
#pragma unroll
    for (int nt = 0; nt < 4; ++nt) acc[nt] = (f32x4){0.f, 0.f, 0.f, 0.f};

#pragma unroll
    for (int ks = 0; ks < K / 32; ++ks) {
#pragma unroll
        for (int nt = 0; nt < 4; ++nt)
            acc[nt] = __builtin_amdgcn_mfma_f32_16x16x32_bf16(afrag[ks], bfrag[nt][ks],
                                                              acc[nt], 0, 0, 0);
    }

#pragma unroll
    for (int i = 0; i < 4; ++i) {
        int gr = rowbase + wave * 16 + quad * 4 + i;
        if (gr < N_NODES) {
            float dsc = dis[gr];
#pragma unroll
            for (int nt = 0; nt < 4; ++nt)
                hb[(long)gr * HID + nt * 16 + m] = f2bf(dsc * acc[nt][i]);
        }
    }
}

// ---------------------------------------------------------------- aggregate (gather)
// A wave's 2 consecutive nodes have CONTIGUOUS csr ranges (bucket-local prefix
// sums; pairs never straddle a bucket). So the wave streams ONE range [s,e1)
// with split e0, and ALL csr addresses (incl. clamped tail) are known as soon
// as rowse lands. Chain: front loads -> all csr (blk0,blk1,tail) -> all
// gathers -> FMA. ~3 dependent round-trips. Rare nf>2 overflow runs a serial
// per-block loop. Routing to acc0/acc1: wave-uniform compare vs e0; predicated
// only for the straddling block and tail. s/e0/e1 scalarized via readfirstlane.
// OB=true : write bf16 rows (layer-1 out, consumed by gemm2).
// OB=false: fused global-mean-pool epilogue (LDS stage + run-length atomics).

#define GATH4(x0_, x1_, x2_, x3_, q0_, q1_, q2_, q3_)                         \
    do {                                                                      \
        q0_ = vh.ld64(((x0_ & 0x1FFFF) << 7) | coff);                         \
        q1_ = vh.ld64(((x1_ & 0x1FFFF) << 7) | coff);                         \
        q2_ = vh.ld64(((x2_ & 0x1FFFF) << 7) | coff);                         \
        q3_ = vh.ld64(((x3_ & 0x1FFFF) << 7) | coff);                         \
    } while (0)

#define ROUTE4(pb_, x0_, x1_, x2_, x3_, q0_, q1_, q2_, q3_)                   \
    do {                                                                      \
        f32x4 v0_ = bf4v(q0_), v1_ = bf4v(q1_);                               \
        f32x4 v2_ = bf4v(q2_), v3_ = bf4v(q3_);                               \
        float w0_ = dec_ew(x0_), w1_ = dec_ew(x1_);                           \
        float w2_ = dec_ew(x2_), w3_ = dec_ew(x3_);                           \
        if (pb_ + 16 <= e0) {                                                 \
            acc0 += v0_ * w0_; acc0 += v1_ * w1_;                             \
            acc0 += v2_ * w2_; acc0 += v3_ * w3_;                             \
        } else if (pb_ >= e0) {                                               \
            acc1 += v0_ * w0_; acc1 += v1_ * w1_;                             \
            acc1 += v2_ * w2_; acc1 += v3_ * w3_;                             \
        } else {                                                              \
            float a0_ = (pb_ + g      < e0) ? w0_ : 0.f;                      \
            float a1_ = (pb_ + 4 + g  < e0) ? w1_ : 0.f;                      \
            float a2_ = (pb_ + 8 + g  < e0) ? w2_ : 0.f;                      \
            float a3_ = (pb_ + 12 + g < e0) ? w3_ : 0.f;                      \
            acc0 += v0_ * a0_; acc1 += v0_ * (w0_ - a0_);                     \
            acc0 += v1_ * a1_; acc1 += v1_ * (w1_ - a1_);                     \
            acc0 += v2_ * a2_; acc1 += v2_ * (w2_ - a2_);                     \
            acc0 += v3_ * a3_; acc1 += v3_ * (w3_ - a3_);                     \
        }                                                                     \
    } while (0)

template <bool OB>
__global__ void k_aggregate(const int2* __restrict__ rowse,
                            const unsigned* __restrict__ csr,
                            const uint2* __restrict__ hb, const float* __restrict__ dis,
                            const float* __restrict__ b, const int* __restrict__ batch,
                            float* __restrict__ pooled, uint2* __restrict__ outb) {
    __shared__ float psh[4 * AGG_NPW][HID];   // 2 KB, used only when !OB
    const int tid  = threadIdx.x;
    const int lane = tid & 63;
    const int g    = lane >> 4;          // edge group 0..3
    const int c4   = lane & 15;          // channel quad index
    const int wave = tid >> 6;
    const int node0 = (blockIdx.x * 4 + wave) * AGG_NPW;   // exact cover
    const int node1 = node0 + 1;
    const float4 bb = ((const float4*)b)[c4];
    const f32x4 bbv = {bb.x, bb.y, bb.z, bb.w};

    BufView vc; vc.init(csr);
    BufView vh; vh.init(hb);
    const unsigned coff = (unsigned)(c4 << 3);   // byte offset of my 8B slice in 128B row

    // ---- front loads, all independent, issued together
    const int4 rr = *(const int4*)&rowse[node0];  // {s, e0, e0, e1} (contiguous)
    const uint2 hs0 = hb[node0 * 16 + c4];
    const uint2 hs1 = hb[node1 * 16 + c4];
    const float dd0 = dis[node0];
    const float dd1 = dis[node1];
    int4 bq0, bq1;
    if constexpr (!OB) {
        if (tid < HID) {   // wave 0: prefetch the block's 8 batch ids
            bq0 = ((const int4*)(batch + blockIdx.x * 4 * AGG_NPW))[0];
            bq1 = ((const int4*)(batch + blockIdx.x * 4 * AGG_NPW))[1];
        }
    }

    const int s  = __builtin_amdgcn_readfirstlane(rr.x);
    const int e0 = __builtin_amdgcn_readfirstlane(rr.y);
    const int e1 = __builtin_amdgcn_readfirstlane(rr.w);

    f32x4 acc0 = (g == 0) ? bf4v(hs0) : (f32x4){0.f, 0.f, 0.f, 0.f};
    f32x4 acc1 = (g == 0) ? bf4v(hs1) : (f32x4){0.f, 0.f, 0.f, 0.f};

    const int nf = (e1 - s) >> 4;        // full 16-edge blocks in combined range
    const int pt = s + (nf << 4);        // tail start
    const bool h0 = (nf >= 1);
    const bool h1 = (nf >= 2);
    const bool hm = (nf > 2);            // rare overflow
    const bool ht = (pt < e1);

    // ---- issue ALL csr loads (blk0, blk1, tail) — independent addresses
    unsigned c0 = 0, c1 = 0, c2 = 0, c3 = 0;
    unsigned d0 = 0, d1 = 0, d2 = 0, d3 = 0;
    unsigned t0 = 0, t1 = 0, t2 = 0, t3 = 0;
    if (h0) {
        const unsigned v = (unsigned)((s + g) << 2);
        c0 = vc.ld32(v);      c1 = vc.ld32(v + 16);
        c2 = vc.ld32(v + 32); c3 = vc.ld32(v + 48);
    }
    if (h1) {
        const unsigned v = (unsigned)((s + 16 + g) << 2);
        d0 = vc.ld32(v);      d1 = vc.ld32(v + 16);
        d2 = vc.ld32(v + 32); d3 = vc.ld32(v + 48);
    }
    if (ht) {
        const int last = e1 - 1;
        t0 = vc.ld32((unsigned)(min(pt + g,      last) << 2));
        t1 = vc.ld32((unsigned)(min(pt + 4 + g,  last) << 2));
        t2 = vc.ld32((unsigned)(min(pt + 8 + g,  last) << 2));
        t3 = vc.ld32((unsigned)(min(pt + 12 + g, last) << 2));
    }

    // ---- issue ALL row gathers back-to-back, then FMA
    uint2 r00, r01, r02, r03, r10, r11, r12, r13, rt0, rt1, rt2, rt3;
    if (h0) GATH4(c0, c1, c2, c3, r00, r01, r02, r03);
    if (h1) GATH4(d0, d1, d2, d3, r10, r11, r12, r13);
    if (ht) GATH4(t0, t1, t2, t3, rt0, rt1, rt2, rt3);

    if (h0) ROUTE4(s,      c0, c1, c2, c3, r00, r01, r02, r03);
    if (h1) ROUTE4(s + 16, d0, d1, d2, d3, r10, r11, r12, r13);

    if (hm) {   // overflow blocks (serial csr->gather per block; rare)
        for (int p = s + 32; p + 16 <= e1; p += 16) {
            unsigned m0, m1, m2, m3;
            uint2 q0, q1, q2, q3;
            const unsigned v = (unsigned)((p + g) << 2);
            m0 = vc.ld32(v);      m1 = vc.ld32(v + 16);
            m2 = vc.ld32(v + 32); m3 = vc.ld32(v + 48);
            GATH4(m0, m1, m2, m3, q0, q1, q2, q3);
            ROUTE4(p, m0, m1, m2, m3, q0, q1, q2, q3);
        }
    }

    if (ht) {   // tail: bounds-clamped weights + routing
        f32x4 v0 = bf4v(rt0), v1 = bf4v(rt1), v2 = bf4v(rt2), v3 = bf4v(rt3);
        const int i0 = pt + g, i1 = pt + 4 + g, i2 = pt + 8 + g, i3 = pt + 12 + g;
        float w0 = (i0 < e1) ? dec_ew(t0) : 0.f;
        float w1 = (i1 < e1) ? dec_ew(t1) : 0.f;
        float w2 = (i2 < e1) ? dec_ew(t2) : 0.f;
        float w3 = (i3 < e1) ? dec_ew(t3) : 0.f;
        float a0 = (i0 < e0) ? w0 : 0.f;
        float a1 = (i1 < e0) ? w1 : 0.f;
        float a2 = (i2 < e0) ? w2 : 0.f;
        float a3 = (i3 < e0) ? w3 : 0.f;
        acc0 += v0 * a0; acc1 += v0 * (w0 - a0);
        acc0 += v1 * a1; acc1 += v1 * (w1 - a1);
        acc0 += v2 * a2; acc1 += v2 * (w2 - a2);
        acc0 += v3 * a3; acc1 += v3 * (w3 - a3);
    }

    // ---- cross-group reduce (4 groups of 16 lanes hold partial sums)
#pragma unroll
    for (int i = 0; i < 4; ++i) {
        float u0 = acc0[i];
        u0 += __shfl_xor(u0, 16); u0 += __shfl_xor(u0, 32);
        acc0[i] = u0;
        float u1 = acc1[i];
        u1 += __shfl_xor(u1, 16); u1 += __shfl_xor(u1, 32);
        acc1[i] = u1;
    }

    if (g == 0) {
        f32x4 o0 = acc0 * dd0 + bbv;
        f32x4 o1 = acc1 * dd1 + bbv;
        o0.x = fmaxf(o0.x, 0.f); o0.y = fmaxf(o0.y, 0.f);
        o0.z = fmaxf(o0.z, 0.f); o0.w = fmaxf(o0.w, 0.f);
        o1.x = fmaxf(o1.x, 0.f); o1.y = fmaxf(o1.y, 0.f);
        o1.z = fmaxf(o1.z, 0.f); o1.w = fmaxf(o1.w, 0.f);
        if constexpr (OB) {
            uint2 pk0, pk1;
            pk0.x = (unsigned)f2bf(o0.x) | ((unsigned)f2bf(o0.y) << 16);
            pk0.y = (unsigned)f2bf(o0.z) | ((unsigned)f2bf(o0.w) << 16);
            pk1.x = (unsigned)f2bf(o1.x) | ((unsigned)f2bf(o1.y) << 16);
            pk1.y = (unsigned)f2bf(o1.z) | ((unsigned)f2bf(o1.w) << 16);
            outb[node0 * 16 + c4] = pk0;
            outb[node1 * 16 + c4] = pk1;
        } else {
            *(f32x4*)&psh[wave * AGG_NPW][c4 * 4] = o0;
            *(f32x4*)&psh[wave * AGG_NPW + 1][c4 * 4] = o1;
        }
    }

    if constexpr (!OB) {   // fused mean-pool: run-length flush (batch sorted)
        __syncthreads();
        if (tid < HID) {
            float a = psh[0][tid];
            int curg = bq0.x;
#define PSTEP(bg_, j_)                                                        \
            if (bg_ != curg) {                                                \
                atomicAdd(&pooled[curg * HID + tid], a);                      \
                a = 0.f; curg = bg_;                                          \
            }                                                                 \
            a += psh[j_][tid];
            PSTEP(bq0.y, 1) PSTEP(bq0.z, 2) PSTEP(bq0.w, 3)
            PSTEP(bq1.x, 4) PSTEP(bq1.y, 5) PSTEP(bq1.z, 6) PSTEP(bq1.w, 7)
#undef PSTEP
            atomicAdd(&pooled[curg * HID + tid], a);
        }
    }
}

// ---------------------------------------------------------------- head
// cnt[g] recovered by binary search over the sorted batch array.
__global__ __launch_bounds__(1024) void k_out(const float* __restrict__ pooled,
                      const int* __restrict__ batch,
                      const float* __restrict__ Wl, const float* __restrict__ bl,
                      float* __restrict__ out) {
    __shared__ int bnd[N_GRAPHS + 1];
    int tid = threadIdx.x;              // 1024 threads
    if (tid <= N_GRAPHS) {
        int target = tid;               // first idx with batch[idx] >= target
        int lo = 0, hi = N_NODES;
        while (lo < hi) {
            int mid = (lo + hi) >> 1;
            if (batch[mid] < target) lo = mid + 1; else hi = mid;
        }
        bnd[tid] = lo;
    }
    __syncthreads();
    int g = tid >> 4, k = tid & 15;
    float cntg = (float)(bnd[g + 1] - bnd[g]);
    float inv = 1.0f / fmaxf(cntg, 1.0f);
    float acc = 0.f;
#pragma unroll
    for (int h = 0; h < HID; ++h) acc += pooled[g * HID + h] * Wl[h * N_CLASSES + k];
    out[g * N_CLASSES + k] = acc * inv + bl[k];
}

extern "C" void kernel_launch(void* const* d_in, const int* in_sizes, int n_in,
                              void* d_out, int out_size, void* d_ws, size_t ws_size,
                              hipStream_t stream) {
    const float* x     = (const float*)d_in[0];
    const int*   ei    = (const int*)d_in[1];
    const float* ew    = (const float*)d_in[2];
    const int*   batch = (const int*)d_in[3];
    const float* W1    = (const float*)d_in[4];
    const float* b1    = (const float*)d_in[5];
    const float* W2    = (const float*)d_in[6];
    const float* b2    = (const float*)d_in[7];
    const float* Wl    = (const float*)d_in[8];
    const float* bl    = (const float*)d_in[9];

    const int* srcv = ei;            // edge_index[0]
    const int* dstv = ei + N_EDGES;  // edge_index[1]

    // workspace layout (all offsets 16B-aligned)
    char* wsb = (char*)d_ws;
    float*          dis    = (float*)wsb;              wsb += 100352 * 4;
    int2*           rowse  = (int2*)wsb;               wsb += 100352 * 8;   // {beg,end}/node
    int*            bcursor= (int*)wsb;                wsb += 256 * 4;
    unsigned*       csr    = (unsigned*)wsb;           wsb += (size_t)NB * BK_CAP * 4;
    unsigned short* hb     = (unsigned short*)wsb;     wsb += N_NODES * HID * 2;  // bf16 dis*h
    char*           scratch= wsb;                      wsb += N_NODES * HID * 4;
    float*          pooled = (float*)wsb;              wsb += N_GRAPHS * HID * 4;
    float*          out    = (float*)d_out;
    int2*           bedges = (int2*)scratch;           // dead after k_build
    unsigned short* hbA    = (unsigned short*)scratch; // layer-1 agg out (bf16), read by gemm2

    // ---- CSR build (counting sort, fixed-capacity buckets, fused build)
    k_init<<<16, 256, 0, stream>>>(bcursor, pooled);
    k_binscatter<<<NCH, 256, 0, stream>>>(srcv, dstv, ew, bcursor, bedges);
    k_build<<<NB, 256, 0, stream>>>(bcursor, bedges, rowse, dis, csr);

    const int agg_blocks = N_NODES / (4 * AGG_NPW);   // 12500, exact

    // ---- layer 1
    k_gemm<IN_CH, false><<<(N_NODES + 63) / 64, 256, 0, stream>>>(x, nullptr, W1, dis, hb);
    k_aggregate<true><<<agg_blocks, 256, 0, stream>>>(rowse, csr, (const uint2*)hb,
                                                      dis, b1, batch, nullptr, (uint2*)hbA);
    // ---- layer 2 (+ fused mean-pool)
    k_gemm<HID, true><<<(N_NODES + 63) / 64, 256, 0, stream>>>(nullptr, hbA, W2, dis, hb);
    k_aggregate<false><<<agg_blocks, 256, 0, stream>>>(rowse, csr, (const uint2*)hb,
                                                       dis, b2, batch, pooled, nullptr);

    // ---- head
    k_out<<<1, 1024, 0, stream>>>(pooled, batch, Wl, bl, out);
}